// Round 4
// baseline (353.841 us; speedup 1.0000x reference)
//
#include <hip/hip_runtime.h>

// B=2,T=4,V=4,H=128,W=128, NQ=64, QDIM=256, IDIM=32, MDIM=16
#define BT     8
#define VHW    (4*128*128)
#define NQn    64
#define QD     256
#define ID     32
#define MD     16
#define CD     48
#define APW    65          // assignment_prob row width (bg + 64 fg)
#define ROWS   128         // rows per tile
#define TPB    4           // tiles per block (register double-buffer prefetch)

typedef short bf16x8 __attribute__((ext_vector_type(8)));
typedef float f32x4  __attribute__((ext_vector_type(4)));

// fp32 -> bf16 RNE, independent of __hip_bfloat16 internals
static __device__ __forceinline__ short f2bf(float f) {
    unsigned u = __builtin_bit_cast(unsigned, f);
    unsigned r = (u + 0x7FFFu + ((u >> 16) & 1u)) >> 16;
    return (short)r;
}

// Kernel A: project query_feat -> bf16 table PRE-PACKED in MFMA B-fragment layout.
// Grid = BT*NQn = 512 blocks (one per (bt,q) row), 256 threads: 4-way k-split.
__global__ __launch_bounds__(256) void qproj_kernel(
    const float* __restrict__ qf,   // [BT*64][256]
    const float* __restrict__ Wi,   // [256][32]
    const float* __restrict__ bi,   // [32]
    const float* __restrict__ Wm,   // [256][16]
    const float* __restrict__ bm,   // [16]
    short* __restrict__ qtabB)      // [BT][3][2][64][8] bf16
{
    __shared__ float part[4][CD];
    const int btq = blockIdx.x;          // bt*64 + q
    const int bt  = btq >> 6;
    const int q   = btq & 63;
    const int ks  = threadIdx.x >> 6;    // k-chunk
    const int d   = threadIdx.x & 63;

    if (d < CD) {
        const float* __restrict__ qrow = qf + btq * QD + ks * 64;
        float a = 0.f;
        if (d < ID) {
            #pragma unroll 8
            for (int j = 0; j < 64; ++j) a = fmaf(qrow[j], Wi[(ks*64 + j)*ID + d], a);
        } else {
            const int dm = d - ID;
            #pragma unroll 8
            for (int j = 0; j < 64; ++j) a = fmaf(qrow[j], Wm[(ks*64 + j)*MD + dm], a);
        }
        part[ks][d] = a;
    }
    __syncthreads();
    if (ks == 0 && d < CD) {
        float s = (d < ID ? bi[d] : bm[d - ID])
                + part[0][d] + part[1][d] + part[2][d] + part[3][d];
        const int nt = d >> 4, c = d & 15;
        const int kt = q >> 5, kk = q & 31;
        const int lane = ((kk >> 3) << 4) | c;
        const int j    = kk & 7;
        qtabB[((((bt*3 + nt)*2 + kt) << 6) + lane) * 8 + j] = f2bf(s);
    }
}

// Kernel B: barrier-free, LDS-free, multi-tile per block with register
// double-buffered ap prefetch. Each wave owns 32 rows per tile (2 M-tiles).
// Load order per tile: ia/mc (current, frag order) -> ap prefetch (next tile)
// -> psum shuffles -> MFMA -> epilogue. In-order vmcnt retirement means the
// epilogue's wait on ia/mc (older) never drains the newer prefetch loads.
__global__ __launch_bounds__(256, 3) void entity_kernel(
    const float* __restrict__ ia,     // [BT*VHW][32]
    const float* __restrict__ mc,     // [BT*VHW][16]
    const float* __restrict__ ap,     // [BT*VHW][65]
    const int*   __restrict__ aq,     // [BT*VHW]
    const short* __restrict__ qtabB,  // [BT][3][2][64][8] bf16
    float* __restrict__ out_id,
    float* __restrict__ out_inst,     // [BT*VHW][32]
    float* __restrict__ out_mot)      // [BT*VHW][16]
{
    const int t    = threadIdx.x;
    const int lane = t & 63;
    const int w    = t >> 6;              // wave 0..3
    const int c    = lane & 15;           // frag col / A row-within-tile
    const int g    = lane >> 4;           // k-group / C row-group
    const int bt   = blockIdx.x >> 9;     // 512 blocks per bt (4096 blocks / 8 bt)
    const long tile0 = (long)blockIdx.x * TPB;

    // ---- B fragments: coalesced 16B loads from pre-packed table (L2-hot) ----
    bf16x8 Bf[3][2];
    {
        const bf16x8* __restrict__ qb = (const bf16x8*)(qtabB + bt * (3*2*64*8));
        #pragma unroll
        for (int nt = 0; nt < 3; ++nt)
            #pragma unroll
            for (int kt = 0; kt < 2; ++kt)
                Bf[nt][kt] = qb[(nt*2 + kt) * 64 + lane];
    }

    // Double-buffered per-tile state (all indices compile-time constants)
    float Af[2][2][2][8];   // [buf][m][kt][j]
    float bg[2][2];         // [buf][m]
    float idv[2];           // [buf]

    // A row = rb + m*16 + c ; k = kt*32 + g*8 + j ; ap col = 1 + k
#define LOAD_AP(BUF, TI) do {                                                  \
    const long rb_ = (TI) * ROWS + w * 32;                                     \
    _Pragma("unroll")                                                          \
    for (int m = 0; m < 2; ++m) {                                              \
        const float* __restrict__ arow = ap + (rb_ + m*16 + c) * APW;          \
        bg[BUF][m] = arow[0];                                                  \
        _Pragma("unroll")                                                      \
        for (int kt = 0; kt < 2; ++kt) {                                       \
            const float* __restrict__ ar = arow + 1 + kt*32 + g*8;             \
            _Pragma("unroll")                                                  \
            for (int j = 0; j < 8; ++j) Af[BUF][m][kt][j] = ar[j];             \
        }                                                                      \
    }                                                                          \
    idv[BUF] = (lane < 32) ? (float)aq[rb_ + lane] : 0.f;                      \
} while (0)

#define STEP(BUF, OTH, TT) do {                                                \
    const long rb = (tile0 + (TT)) * ROWS + w * 32;                            \
    /* current-tile epilogue operands, frag order (issued BEFORE prefetch) */  \
    float ia_r[2][2][4], mc_r[2][4];                                           \
    _Pragma("unroll")                                                          \
    for (int m = 0; m < 2; ++m)                                                \
        _Pragma("unroll")                                                      \
        for (int r = 0; r < 4; ++r) {                                          \
            const long row = rb + m*16 + 4*g + r;                              \
            ia_r[m][0][r] = ia[row*ID + c];                                    \
            ia_r[m][1][r] = ia[row*ID + 16 + c];                               \
            mc_r[m][r]    = mc[row*MD + c];                                    \
        }                                                                      \
    /* prefetch next tile's ap into the other buffer (stays in flight) */      \
    if ((TT) + 1 < TPB) LOAD_AP(OTH, tile0 + (TT) + 1);                        \
    /* psum (fp32) + scale, in-register: row (m*16+c)'s probs live in */       \
    /* lanes {c, c+16, c+32, c+48} */                                          \
    float scale[2][4];                                                         \
    _Pragma("unroll")                                                          \
    for (int m = 0; m < 2; ++m) {                                              \
        float s = 0.f;                                                         \
        _Pragma("unroll")                                                      \
        for (int kt = 0; kt < 2; ++kt)                                         \
            _Pragma("unroll")                                                  \
            for (int j = 0; j < 8; ++j) s += Af[BUF][m][kt][j];                \
        s += __shfl_xor(s, 16);                                                \
        s += __shfl_xor(s, 32);                                                \
        const float sc = (1.0f - bg[BUF][m]) / fmaxf(s, 1e-6f);                \
        _Pragma("unroll")                                                      \
        for (int r = 0; r < 4; ++r) scale[m][r] = __shfl(sc, 4*g + r);         \
    }                                                                          \
    /* pack A to bf16, MFMA */                                                 \
    bf16x8 Ab[2][2];                                                           \
    _Pragma("unroll")                                                          \
    for (int m = 0; m < 2; ++m)                                                \
        _Pragma("unroll")                                                      \
        for (int kt = 0; kt < 2; ++kt)                                         \
            _Pragma("unroll")                                                  \
            for (int j = 0; j < 8; ++j) Ab[m][kt][j] = f2bf(Af[BUF][m][kt][j]);\
    f32x4 acc[2][3];                                                           \
    _Pragma("unroll")                                                          \
    for (int m = 0; m < 2; ++m)                                                \
        _Pragma("unroll")                                                      \
        for (int n = 0; n < 3; ++n) acc[m][n] = (f32x4){0.f,0.f,0.f,0.f};      \
    _Pragma("unroll")                                                          \
    for (int kt = 0; kt < 2; ++kt)                                             \
        _Pragma("unroll")                                                      \
        for (int m = 0; m < 2; ++m) {                                          \
            acc[m][0] = __builtin_amdgcn_mfma_f32_16x16x32_bf16(Ab[m][kt], Bf[0][kt], acc[m][0], 0, 0, 0); \
            acc[m][1] = __builtin_amdgcn_mfma_f32_16x16x32_bf16(Ab[m][kt], Bf[1][kt], acc[m][1], 0, 0, 0); \
            acc[m][2] = __builtin_amdgcn_mfma_f32_16x16x32_bf16(Ab[m][kt], Bf[2][kt], acc[m][2], 0, 0, 0); \
        }                                                                      \
    /* epilogue: residual add + store in fragment order */                     \
    _Pragma("unroll")                                                          \
    for (int m = 0; m < 2; ++m)                                                \
        _Pragma("unroll")                                                      \
        for (int r = 0; r < 4; ++r) {                                          \
            const long row = rb + m*16 + 4*g + r;                              \
            const float s = scale[m][r];                                       \
            out_inst[row*ID + c]      = ia_r[m][0][r] + s * acc[m][0][r];      \
            out_inst[row*ID + 16 + c] = ia_r[m][1][r] + s * acc[m][1][r];      \
            out_mot [row*MD + c]      = mc_r[m][r]    + s * acc[m][2][r];      \
        }                                                                      \
    if (lane < 32) out_id[rb + lane] = idv[BUF];                               \
} while (0)

    LOAD_AP(0, tile0);
    STEP(0, 1, 0);
    STEP(1, 0, 1);
    STEP(0, 1, 2);
    STEP(1, 0, 3);

#undef STEP
#undef LOAD_AP
}

extern "C" void kernel_launch(void* const* d_in, const int* in_sizes, int n_in,
                              void* d_out, int out_size, void* d_ws, size_t ws_size,
                              hipStream_t stream) {
    const float* ia = (const float*)d_in[0];
    const float* mc = (const float*)d_in[1];
    const float* qf = (const float*)d_in[2];
    const float* ap = (const float*)d_in[3];
    const int*   aq = (const int*)  d_in[4];
    const float* Wi = (const float*)d_in[5];
    const float* bi = (const float*)d_in[6];
    const float* Wm = (const float*)d_in[7];
    const float* bm = (const float*)d_in[8];

    short* qtabB = (short*)d_ws;                       // 8*3*2*64*8*2 = 49,152 B

    float* out_id   = (float*)d_out;
    float* out_inst = out_id + (long)BT * VHW;
    float* out_mot  = out_inst + (long)BT * VHW * ID;

    qproj_kernel<<<BT * NQn, 256, 0, stream>>>(qf, Wi, bi, Wm, bm, qtabB);
    entity_kernel<<<(BT * VHW) / (TPB * ROWS), 256, 0, stream>>>(ia, mc, ap, aq, qtabB,
                                                                 out_id, out_inst, out_mot);
}

// Round 5
// 310.308 us; speedup vs baseline: 1.1403x; 1.1403x over previous
//
#include <hip/hip_runtime.h>

// B=2,T=4,V=4,H=128,W=128, NQ=64, QDIM=256, IDIM=32, MDIM=16
#define BT     8
#define VHW    (4*128*128)
#define NQn    64
#define QD     256
#define ID     32
#define MD     16
#define CD     48
#define APW    65          // assignment_prob row width (bg + 64 fg)

typedef short bf16x8 __attribute__((ext_vector_type(8)));
typedef float f32x4  __attribute__((ext_vector_type(4)));

// fp32 -> bf16 RNE, independent of __hip_bfloat16 internals
static __device__ __forceinline__ short f2bf(float f) {
    unsigned u = __builtin_bit_cast(unsigned, f);
    unsigned r = (u + 0x7FFFu + ((u >> 16) & 1u)) >> 16;
    return (short)r;
}

// Kernel A: project query_feat -> bf16 table PRE-PACKED in MFMA B-fragment layout.
// Grid = BT*NQn = 512 blocks (one per (bt,q) row), 256 threads: 4-way k-split.
__global__ __launch_bounds__(256) void qproj_kernel(
    const float* __restrict__ qf,   // [BT*64][256]
    const float* __restrict__ Wi,   // [256][32]
    const float* __restrict__ bi,   // [32]
    const float* __restrict__ Wm,   // [256][16]
    const float* __restrict__ bm,   // [16]
    short* __restrict__ qtabB)      // [BT][3][2][64][8] bf16
{
    __shared__ float part[4][CD];
    const int btq = blockIdx.x;          // bt*64 + q
    const int bt  = btq >> 6;
    const int q   = btq & 63;
    const int ks  = threadIdx.x >> 6;    // k-chunk
    const int d   = threadIdx.x & 63;

    if (d < CD) {
        const float* __restrict__ qrow = qf + btq * QD + ks * 64;
        float a = 0.f;
        if (d < ID) {
            #pragma unroll 8
            for (int j = 0; j < 64; ++j) a = fmaf(qrow[j], Wi[(ks*64 + j)*ID + d], a);
        } else {
            const int dm = d - ID;
            #pragma unroll 8
            for (int j = 0; j < 64; ++j) a = fmaf(qrow[j], Wm[(ks*64 + j)*MD + dm], a);
        }
        part[ks][d] = a;
    }
    __syncthreads();
    if (ks == 0 && d < CD) {
        float s = (d < ID ? bi[d] : bm[d - ID])
                + part[0][d] + part[1][d] + part[2][d] + part[3][d];
        const int nt = d >> 4, c = d & 15;
        const int kt = q >> 5, kk = q & 31;
        const int lane = ((kk >> 3) << 4) | c;
        const int j    = kk & 7;
        qtabB[((((bt*3 + nt)*2 + kt) << 6) + lane) * 8 + j] = f2bf(s);
    }
}

// Kernel B: barrier-free, LDS-free streaming (R2 structure). Each wave owns 32
// rows (2 M-tiles). A-fragments read directly from global (per-lane contiguous
// 8-float runs), psum via in-register fp32 reduce + 2 shuffles, scale
// redistributed via 4 shuffles, pooled = P @ Q via MFMA, residual-add epilogue
// in fragment order.
// R5 changes: __launch_bounds__(256,3) raises the VGPR cap to ~170 so ALL load
// results stay live; sched_barrier(0) after the load cluster stops the compiler
// from sinking loads into the consumer code (R2/R4 showed it batch-serializes
// them at VGPR<=84, paying ~8 sequential memory latencies per wave).
__global__ __launch_bounds__(256, 3) void entity_kernel(
    const float* __restrict__ ia,     // [BT*VHW][32]
    const float* __restrict__ mc,     // [BT*VHW][16]
    const float* __restrict__ ap,     // [BT*VHW][65]
    const int*   __restrict__ aq,     // [BT*VHW]
    const short* __restrict__ qtabB,  // [BT][3][2][64][8] bf16
    float* __restrict__ out_id,
    float* __restrict__ out_inst,     // [BT*VHW][32]
    float* __restrict__ out_mot)      // [BT*VHW][16]
{
    const int t    = threadIdx.x;
    const int lane = t & 63;
    const int w    = t >> 6;              // wave 0..3
    const int c    = lane & 15;           // frag col / A row-within-tile
    const int g    = lane >> 4;           // k-group / C row-group
    const int bt   = blockIdx.x >> 9;     // 4096 blocks / 8 bt = 512 blocks per bt
    const long rb  = (long)blockIdx.x * 128 + w * 32;   // wave's first row

    // ---- B fragments: coalesced 16B loads from pre-packed table (L2-hot) ----
    bf16x8 Bf[3][2];
    {
        const bf16x8* __restrict__ qb = (const bf16x8*)(qtabB + bt * (3*2*64*8));
        #pragma unroll
        for (int nt = 0; nt < 3; ++nt)
            #pragma unroll
            for (int kt = 0; kt < 2; ++kt)
                Bf[nt][kt] = qb[(nt*2 + kt) * 64 + lane];
    }

    // ---- A fragments (raw fp32) + bg, straight from global ----
    // A row = rb + m*16 + c ; k = kt*32 + g*8 + j ; ap col = 1 + k
    float Af[2][2][8];
    float bg[2];
    #pragma unroll
    for (int m = 0; m < 2; ++m) {
        const float* __restrict__ arow = ap + (rb + m*16 + c) * APW;
        bg[m] = arow[0];
        #pragma unroll
        for (int kt = 0; kt < 2; ++kt) {
            const float* __restrict__ ar = arow + 1 + kt*32 + g*8;
            #pragma unroll
            for (int j = 0; j < 8; ++j) Af[m][kt][j] = ar[j];
        }
    }

    // ---- epilogue operands, fragment order (issued early; consumed last) ----
    // C row = rb + m*16 + 4*g + r, col c (+16 for n=1)
    float ia_r[2][2][4], mc_r[2][4];
    #pragma unroll
    for (int m = 0; m < 2; ++m)
        #pragma unroll
        for (int r = 0; r < 4; ++r) {
            const long row = rb + m*16 + 4*g + r;
            ia_r[m][0][r] = ia[row*ID + c];
            ia_r[m][1][r] = ia[row*ID + 16 + c];
            mc_r[m][r]    = mc[row*MD + c];
        }
    float idv = 0.f;
    if (lane < 32) idv = (float)aq[rb + lane];

    // Pin every load above this point: nothing may sink past here. All ~35
    // VMEM reads issue back-to-back; the waits below then cover ONE latency.
    __builtin_amdgcn_sched_barrier(0);

    // ---- psum (fp32) + scale, all in-register ----
    // row (m*16+c)'s 64 probs live in lanes {c, c+16, c+32, c+48}
    float scale[2][4];
    #pragma unroll
    for (int m = 0; m < 2; ++m) {
        float s = 0.f;
        #pragma unroll
        for (int kt = 0; kt < 2; ++kt)
            #pragma unroll
            for (int j = 0; j < 8; ++j) s += Af[m][kt][j];
        s += __shfl_xor(s, 16);
        s += __shfl_xor(s, 32);
        const float sc = (1.0f - bg[m]) / fmaxf(s, 1e-6f);
        // redistribute to C-fragment rows: row 4g+r comes from lane (4g+r)
        #pragma unroll
        for (int r = 0; r < 4; ++r) scale[m][r] = __shfl(sc, 4*g + r);
    }

    // ---- pack A to bf16, MFMA ----
    bf16x8 Ab[2][2];
    #pragma unroll
    for (int m = 0; m < 2; ++m)
        #pragma unroll
        for (int kt = 0; kt < 2; ++kt)
            #pragma unroll
            for (int j = 0; j < 8; ++j) Ab[m][kt][j] = f2bf(Af[m][kt][j]);

    f32x4 acc[2][3];
    #pragma unroll
    for (int m = 0; m < 2; ++m)
        #pragma unroll
        for (int n = 0; n < 3; ++n) acc[m][n] = (f32x4){0.f, 0.f, 0.f, 0.f};
    #pragma unroll
    for (int kt = 0; kt < 2; ++kt)
        #pragma unroll
        for (int m = 0; m < 2; ++m) {
            acc[m][0] = __builtin_amdgcn_mfma_f32_16x16x32_bf16(Ab[m][kt], Bf[0][kt], acc[m][0], 0, 0, 0);
            acc[m][1] = __builtin_amdgcn_mfma_f32_16x16x32_bf16(Ab[m][kt], Bf[1][kt], acc[m][1], 0, 0, 0);
            acc[m][2] = __builtin_amdgcn_mfma_f32_16x16x32_bf16(Ab[m][kt], Bf[2][kt], acc[m][2], 0, 0, 0);
        }

    // ---- epilogue: residual add + store in fragment order ----
    #pragma unroll
    for (int m = 0; m < 2; ++m)
        #pragma unroll
        for (int r = 0; r < 4; ++r) {
            const long row = rb + m*16 + 4*g + r;
            const float s = scale[m][r];
            out_inst[row*ID + c]      = ia_r[m][0][r] + s * acc[m][0][r];
            out_inst[row*ID + 16 + c] = ia_r[m][1][r] + s * acc[m][1][r];
            out_mot [row*MD + c]      = mc_r[m][r]    + s * acc[m][2][r];
        }
    if (lane < 32) out_id[rb + lane] = idv;
}

extern "C" void kernel_launch(void* const* d_in, const int* in_sizes, int n_in,
                              void* d_out, int out_size, void* d_ws, size_t ws_size,
                              hipStream_t stream) {
    const float* ia = (const float*)d_in[0];
    const float* mc = (const float*)d_in[1];
    const float* qf = (const float*)d_in[2];
    const float* ap = (const float*)d_in[3];
    const int*   aq = (const int*)  d_in[4];
    const float* Wi = (const float*)d_in[5];
    const float* bi = (const float*)d_in[6];
    const float* Wm = (const float*)d_in[7];
    const float* bm = (const float*)d_in[8];

    short* qtabB = (short*)d_ws;                       // 8*3*2*64*8*2 = 49,152 B

    float* out_id   = (float*)d_out;
    float* out_inst = out_id + (long)BT * VHW;
    float* out_mot  = out_inst + (long)BT * VHW * ID;

    qproj_kernel<<<BT * NQn, 256, 0, stream>>>(qf, Wi, bi, Wm, bm, qtabB);
    entity_kernel<<<(BT * VHW) / 128, 256, 0, stream>>>(ia, mc, ap, aq, qtabB,
                                                        out_id, out_inst, out_mot);
}